// Round 2
// baseline (2671.266 us; speedup 1.0000x reference)
//
#include <hip/hip_runtime.h>
#include <math.h>

#define BB 2
#define CC 128
#define CHH 64
#define DD 16
#define NN 4096   // 16*16*16
#define SP 256    // 16*16

// ---------------- K1: pooled = mean over spatial of (mri+pet), per (b,c) ----------------
__global__ __launch_bounds__(256) void k_pool(const float* __restrict__ mri,
                                              const float* __restrict__ pet,
                                              float* __restrict__ pooled) {
    int bc = blockIdx.x;  // 0..255  = b*CC + c
    const float* m = mri + (size_t)bc * NN;
    const float* p = pet + (size_t)bc * NN;
    float s = 0.f;
    for (int i = threadIdx.x; i < NN; i += 256) s += m[i] + p[i];
    __shared__ float red[256];
    red[threadIdx.x] = s;
    __syncthreads();
    for (int off = 128; off > 0; off >>= 1) {
        if (threadIdx.x < off) red[threadIdx.x] += red[threadIdx.x + off];
        __syncthreads();
    }
    if (threadIdx.x == 0) pooled[bc] = red[0] * (1.0f / NN);
}

// ---------------- K2: channel attention MLP -> cw (B,C) ----------------
__global__ __launch_bounds__(128) void k_cw(const float* __restrict__ pooled,
                                            const float* __restrict__ w1, const float* __restrict__ b1,
                                            const float* __restrict__ w2, const float* __restrict__ b2,
                                            float* __restrict__ cw) {
    __shared__ float pl[BB * CC];
    __shared__ float tl[BB * CHH];
    int t = threadIdx.x;  // 0..127
    pl[t] = pooled[t];
    pl[t + 128] = pooled[t + 128];
    __syncthreads();
    {
        int b = t >> 6, h = t & 63;
        float acc = b1[h];
        for (int c = 0; c < CC; c++) acc += pl[b * CC + c] * w1[h * CC + c];
        tl[b * CHH + h] = fmaxf(acc, 0.f);
    }
    __syncthreads();
    for (int b = 0; b < BB; b++) {
        float acc = b2[t];
        for (int h = 0; h < CHH; h++) acc += tl[b * CHH + h] * w2[t * CHH + h];
        cw[b * CC + t] = 1.f / (1.f + __expf(-acc));
    }
}

// ---------------- K3: Q/K/V 1x1 convs with cw folded in; outputs transposed (b,n,c) ----------------
__global__ __launch_bounds__(256) void k_qkv(const float* __restrict__ mri, const float* __restrict__ pet,
                                             const float* __restrict__ cw,
                                             const float* __restrict__ qw, const float* __restrict__ qb,
                                             const float* __restrict__ kw, const float* __restrict__ kb,
                                             const float* __restrict__ vw, const float* __restrict__ vb,
                                             float* __restrict__ Qt, float* __restrict__ Kt, float* __restrict__ Vt) {
    int blk = blockIdx.x;
    int b = blk >> 6;            // 64 n-tiles per batch
    int n0 = (blk & 63) * 64;
    __shared__ float am[CC * 64];  // mri_w tile [c][j]
    __shared__ float ap[CC * 64];  // pet_w tile [c][j]
    int t = threadIdx.x;
    for (int e = t; e < CC * 64; e += 256) {
        int c = e >> 6, j = e & 63;
        float cwv = cw[b * CC + c];
        size_t g = (size_t)(b * CC + c) * NN + n0 + j;
        am[e] = mri[g] * cwv;
        ap[e] = pet[g] * cwv;
    }
    __syncthreads();
    int o = t & 127, half = t >> 7;
    const int jb = half * 32;
    // Q from mri_w
    {
        float acc[32];
        float bias = qb[o];
#pragma unroll
        for (int j = 0; j < 32; j++) acc[j] = bias;
        for (int c = 0; c < CC; c++) {
            float wv = qw[o * CC + c];
            const float* row = &am[c * 64 + jb];
#pragma unroll
            for (int j = 0; j < 32; j++) acc[j] += wv * row[j];
        }
#pragma unroll
        for (int j = 0; j < 32; j++) Qt[((size_t)b * NN + n0 + jb + j) * CC + o] = acc[j];
    }
    // K from pet_w
    {
        float acc[32];
        float bias = kb[o];
#pragma unroll
        for (int j = 0; j < 32; j++) acc[j] = bias;
        for (int c = 0; c < CC; c++) {
            float wv = kw[o * CC + c];
            const float* row = &ap[c * 64 + jb];
#pragma unroll
            for (int j = 0; j < 32; j++) acc[j] += wv * row[j];
        }
#pragma unroll
        for (int j = 0; j < 32; j++) Kt[((size_t)b * NN + n0 + jb + j) * CC + o] = acc[j];
    }
    // V from pet_w
    {
        float acc[32];
        float bias = vb[o];
#pragma unroll
        for (int j = 0; j < 32; j++) acc[j] = bias;
        for (int c = 0; c < CC; c++) {
            float wv = vw[o * CC + c];
            const float* row = &ap[c * 64 + jb];
#pragma unroll
            for (int j = 0; j < 32; j++) acc[j] += wv * row[j];
        }
#pragma unroll
        for (int j = 0; j < 32; j++) Vt[((size_t)b * NN + n0 + jb + j) * CC + o] = acc[j];
    }
}

// ---------------- K4: attention, 8 queries/block ----------------
// NOTE: reference softmax is over the LAST W axis only (groups of 16
// contiguous key positions), not the full 4096-key row.
__global__ __launch_bounds__(256) void k_attn(const float* __restrict__ Qt, const float* __restrict__ Kt,
                                              const float* __restrict__ Vt,
                                              const float* __restrict__ mri, const float* __restrict__ cw,
                                              float* __restrict__ X) {
    __shared__ float q[8 * CC];      // 4 KB
    __shared__ float p[8 * NN];      // 128 KB (gfx950 LDS = 160 KB/CU)
    __shared__ float comb[8 * CC];   // 4 KB
    int blk = blockIdx.x;
    int b = blk >> 9;            // 512 q-tiles per batch
    int n0 = (blk & 511) * 8;
    int t = threadIdx.x;
    for (int e = t; e < 8 * CC; e += 256) {
        int i = e >> 7, c = e & 127;
        q[e] = Qt[((size_t)b * NN + n0 + i) * CC + c];
    }
    __syncthreads();
    int qi = t >> 5;   // query 0..7 (half-wave per query)
    int ln = t & 31;
    const float* qrow = &q[qi * CC];
    const float* Kb = Kt + (size_t)b * NN * CC;
    for (int k = 0; k < 128; k++) {
        int m = k * 32 + ln;
        const float* krow = Kb + (size_t)m * CC;
        float acc = 0.f;
#pragma unroll 8
        for (int c = 0; c < CC; c += 4) {
            float4 kv = *reinterpret_cast<const float4*>(krow + c);
            acc += qrow[c] * kv.x + qrow[c + 1] * kv.y + qrow[c + 2] * kv.z + qrow[c + 3] * kv.w;
        }
        // softmax over each aligned group of 16 keys (last W axis of scores).
        // Lanes [0..15] and [16..31] of this half-wave are exactly the two
        // groups covered at iteration k; xor offsets 8,4,2,1 stay in-group.
        float gmax = acc;
#pragma unroll
        for (int off = 8; off > 0; off >>= 1) gmax = fmaxf(gmax, __shfl_xor(gmax, off));
        float e = __expf(acc - gmax);
        float gsum = e;
#pragma unroll
        for (int off = 8; off > 0; off >>= 1) gsum += __shfl_xor(gsum, off);
        p[qi * NN + m] = e / gsum;   // normalized attention weight
    }
    __syncthreads();
    // PV: thread -> (c, half of m-range); attn weights already normalized
    int c = t & 127, half = t >> 7;
    float acc[8];
#pragma unroll
    for (int i = 0; i < 8; i++) acc[i] = 0.f;
    const float* Vb = Vt + (size_t)b * NN * CC;
    for (int m = half * 2048; m < half * 2048 + 2048; m++) {
        float vv = Vb[(size_t)m * CC + c];
#pragma unroll
        for (int i = 0; i < 8; i++) acc[i] += p[i * NN + m] * vv;
    }
    if (half == 0) {
#pragma unroll
        for (int i = 0; i < 8; i++) comb[i * CC + c] = acc[i];
    }
    __syncthreads();
    if (half == 1) {
        float cwv = cw[b * CC + c];
#pragma unroll
        for (int i = 0; i < 8; i++) {
            float f = comb[i * CC + c] + acc[i];
            int n = n0 + i;
            size_t gi = ((size_t)b * CC + c) * NN + n;
            X[gi] = f + mri[gi] * cwv;   // x = fused + mri_w
        }
    }
}

// ---------------- K5: 3x3x3 conv (C->CH) + bias + ReLU + BN ----------------
__global__ __launch_bounds__(256) void k_conv3(const float* __restrict__ X,
                                               const float* __restrict__ c1w, const float* __restrict__ c1b,
                                               const float* __restrict__ g, const float* __restrict__ be,
                                               const float* __restrict__ mean, const float* __restrict__ var,
                                               float* __restrict__ Y) {
    int blk = blockIdx.x;                 // b*CHH*DD blocks
    int b = blk >> 10, h = (blk >> 4) & 63, d = blk & 15;
    __shared__ float wl[CC * 27];         // 13.8 KB
    int t = threadIdx.x;
    for (int e = t; e < CC * 27; e += 256) wl[e] = c1w[h * CC * 27 + e];
    __syncthreads();
    int hh = t >> 4, ww = t & 15;
    const float* xb = X + (size_t)b * CC * NN;
    float acc = 0.f;
    for (int c = 0; c < CC; c++) {
        const float* xc = xb + (size_t)c * NN;
        const float* wc = &wl[c * 27];
#pragma unroll
        for (int kd = 0; kd < 3; kd++) {
            int id = d + kd - 1;
            if ((unsigned)id >= 16u) continue;   // block-uniform
#pragma unroll
            for (int kh = 0; kh < 3; kh++) {
                int ih = hh + kh - 1;
                bool vh = (unsigned)ih < 16u;
#pragma unroll
                for (int kw = 0; kw < 3; kw++) {
                    int iw = ww + kw - 1;
                    bool v = vh && ((unsigned)iw < 16u);
                    float xv = v ? xc[id * 256 + ih * 16 + iw] : 0.f;
                    acc += xv * wc[kd * 9 + kh * 3 + kw];
                }
            }
        }
    }
    acc = fmaxf(acc + c1b[h], 0.f);
    float iv = rsqrtf(var[h] + 1e-5f);
    acc = (acc - mean[h]) * (g[h] * iv) + be[h];
    Y[((size_t)b * CHH + h) * NN + d * 256 + t] = acc;
}

// ---------------- K6: final 1x1 conv (CH->C) ----------------
__global__ __launch_bounds__(256) void k_out(const float* __restrict__ Y,
                                             const float* __restrict__ w2, const float* __restrict__ b2,
                                             float* __restrict__ out) {
    int blk = blockIdx.x;  // B*CC blocks
    int b = blk >> 7, o = blk & 127;
    __shared__ float wl[CHH];
    if (threadIdx.x < CHH) wl[threadIdx.x] = w2[o * CHH + threadIdx.x];
    __syncthreads();
    float bias = b2[o];
    const float* yb = Y + (size_t)b * CHH * NN;
    for (int n = threadIdx.x; n < NN; n += 256) {
        float acc = bias;
#pragma unroll 8
        for (int hh = 0; hh < CHH; hh++) acc += wl[hh] * yb[(size_t)hh * NN + n];
        out[((size_t)b * CC + o) * NN + n] = acc;
    }
}

extern "C" void kernel_launch(void* const* d_in, const int* in_sizes, int n_in,
                              void* d_out, int out_size, void* d_ws, size_t ws_size,
                              hipStream_t stream) {
    const float* mri = (const float*)d_in[0];
    const float* pet = (const float*)d_in[1];
    const float* qw  = (const float*)d_in[2];
    const float* qb  = (const float*)d_in[3];
    const float* kw  = (const float*)d_in[4];
    const float* kb  = (const float*)d_in[5];
    const float* vw  = (const float*)d_in[6];
    const float* vb  = (const float*)d_in[7];
    const float* w1  = (const float*)d_in[8];
    const float* b1  = (const float*)d_in[9];
    const float* w2  = (const float*)d_in[10];
    const float* b2  = (const float*)d_in[11];
    const float* c1w = (const float*)d_in[12];
    const float* c1b = (const float*)d_in[13];
    const float* bg  = (const float*)d_in[14];
    const float* bbeta = (const float*)d_in[15];
    const float* bm  = (const float*)d_in[16];
    const float* bv  = (const float*)d_in[17];
    const float* c2w = (const float*)d_in[18];
    const float* c2b = (const float*)d_in[19];
    float* out = (float*)d_out;

    float* ws = (float*)d_ws;
    float* pooled = ws;                         // 256
    float* cw = ws + 256;                       // 256
    float* Qt = ws + 512;                       // B*N*C
    float* Kt = Qt + (size_t)BB * NN * CC;
    float* Vt = Kt + (size_t)BB * NN * CC;
    float* X  = Vt + (size_t)BB * NN * CC;      // (b,c,n)
    float* Y  = X  + (size_t)BB * CC * NN;      // (b,h,n)

    k_pool<<<BB * CC, 256, 0, stream>>>(mri, pet, pooled);
    k_cw<<<1, 128, 0, stream>>>(pooled, w1, b1, w2, b2, cw);
    k_qkv<<<BB * (NN / 64), 256, 0, stream>>>(mri, pet, cw, qw, qb, kw, kb, vw, vb, Qt, Kt, Vt);
    k_attn<<<BB * (NN / 8), 256, 0, stream>>>(Qt, Kt, Vt, mri, cw, X);
    k_conv3<<<BB * CHH * DD, 256, 0, stream>>>(X, c1w, c1b, bg, bbeta, bm, bv, Y);
    k_out<<<BB * CC, 256, 0, stream>>>(Y, c2w, c2b, out);
}

// Round 3
// 432.587 us; speedup vs baseline: 6.1751x; 6.1751x over previous
//
#include <hip/hip_runtime.h>
#include <hip/hip_bf16.h>
#include <math.h>

#define BB 2
#define CC 128
#define CHH 64
#define DD 16
#define NN 4096   // 16*16*16
#define SP 256    // 16*16

typedef float  f32x4 __attribute__((ext_vector_type(4)));
typedef short  s16x4 __attribute__((ext_vector_type(4)));
typedef short  s16x8 __attribute__((ext_vector_type(8)));

static __device__ __forceinline__ unsigned short f2bf(float x) {
    __hip_bfloat16 h = __float2bfloat16(x);
    return __builtin_bit_cast(unsigned short, h);
}

// ---------------- K1: pooled = mean over spatial of (mri+pet), per (b,c) ----------------
__global__ __launch_bounds__(256) void k_pool(const float* __restrict__ mri,
                                              const float* __restrict__ pet,
                                              float* __restrict__ pooled) {
    int bc = blockIdx.x;
    const float* m = mri + (size_t)bc * NN;
    const float* p = pet + (size_t)bc * NN;
    float s = 0.f;
    for (int i = threadIdx.x; i < NN; i += 256) s += m[i] + p[i];
    __shared__ float red[256];
    red[threadIdx.x] = s;
    __syncthreads();
    for (int off = 128; off > 0; off >>= 1) {
        if (threadIdx.x < off) red[threadIdx.x] += red[threadIdx.x + off];
        __syncthreads();
    }
    if (threadIdx.x == 0) pooled[bc] = red[0] * (1.0f / NN);
}

// ---------------- K2: channel attention MLP -> cw (B,C) ----------------
__global__ __launch_bounds__(128) void k_cw(const float* __restrict__ pooled,
                                            const float* __restrict__ w1, const float* __restrict__ b1,
                                            const float* __restrict__ w2, const float* __restrict__ b2,
                                            float* __restrict__ cw) {
    __shared__ float pl[BB * CC];
    __shared__ float tl[BB * CHH];
    int t = threadIdx.x;
    pl[t] = pooled[t];
    pl[t + 128] = pooled[t + 128];
    __syncthreads();
    {
        int b = t >> 6, h = t & 63;
        float acc = b1[h];
        for (int c = 0; c < CC; c++) acc += pl[b * CC + c] * w1[h * CC + c];
        tl[b * CHH + h] = fmaxf(acc, 0.f);
    }
    __syncthreads();
    for (int b = 0; b < BB; b++) {
        float acc = b2[t];
        for (int h = 0; h < CHH; h++) acc += tl[b * CHH + h] * w2[t * CHH + h];
        cw[b * CC + t] = 1.f / (1.f + __expf(-acc));
    }
}

// ---------------- K3: Q/K/V 1x1 convs with cw folded; bf16 outputs ----------------
// Qt, Kt: (b, n, c) bf16 ; Vc: (b, c, n) bf16
__global__ __launch_bounds__(256) void k_qkv(const float* __restrict__ mri, const float* __restrict__ pet,
                                             const float* __restrict__ cw,
                                             const float* __restrict__ qw, const float* __restrict__ qb,
                                             const float* __restrict__ kw, const float* __restrict__ kb,
                                             const float* __restrict__ vw, const float* __restrict__ vb,
                                             unsigned short* __restrict__ Qt, unsigned short* __restrict__ Kt,
                                             unsigned short* __restrict__ Vc) {
    int blk = blockIdx.x;
    int b = blk >> 6;
    int n0 = (blk & 63) * 64;
    __shared__ float am[CC * 64];
    __shared__ float ap[CC * 64];
    int t = threadIdx.x;
    for (int e = t; e < CC * 64; e += 256) {
        int c = e >> 6, j = e & 63;
        float cwv = cw[b * CC + c];
        size_t g = (size_t)(b * CC + c) * NN + n0 + j;
        am[e] = mri[g] * cwv;
        ap[e] = pet[g] * cwv;
    }
    __syncthreads();
    int o = t & 127, half = t >> 7;
    const int jb = half * 32;
    {
        float acc[32];
        float bias = qb[o];
#pragma unroll
        for (int j = 0; j < 32; j++) acc[j] = bias;
        for (int c = 0; c < CC; c++) {
            float wv = qw[o * CC + c];
            const float* row = &am[c * 64 + jb];
#pragma unroll
            for (int j = 0; j < 32; j++) acc[j] += wv * row[j];
        }
#pragma unroll
        for (int j = 0; j < 32; j++) Qt[((size_t)b * NN + n0 + jb + j) * CC + o] = f2bf(acc[j]);
    }
    {
        float acc[32];
        float bias = kb[o];
#pragma unroll
        for (int j = 0; j < 32; j++) acc[j] = bias;
        for (int c = 0; c < CC; c++) {
            float wv = kw[o * CC + c];
            const float* row = &ap[c * 64 + jb];
#pragma unroll
            for (int j = 0; j < 32; j++) acc[j] += wv * row[j];
        }
#pragma unroll
        for (int j = 0; j < 32; j++) Kt[((size_t)b * NN + n0 + jb + j) * CC + o] = f2bf(acc[j]);
    }
    {
        float acc[32];
        float bias = vb[o];
#pragma unroll
        for (int j = 0; j < 32; j++) acc[j] = bias;
        for (int c = 0; c < CC; c++) {
            float wv = vw[o * CC + c];
            const float* row = &ap[c * 64 + jb];
#pragma unroll
            for (int j = 0; j < 32; j++) acc[j] += wv * row[j];
        }
#pragma unroll
        for (int j = 0; j < 32; j++) Vc[((size_t)b * CC + o) * NN + n0 + jb + j] = f2bf(acc[j]);
    }
}

// ---------------- K4: MFMA attention ----------------
// Sᵀ = K·Qᵀ per 16-key tile (= one softmax group); softmax in-register;
// P regs are directly the PV B-fragment; O accumulated as Oᵀ[c][q].
// Block: 512 thr = 8 waves; 32 queries/block; waves split keys 8-way.
#define QW 32
__global__ __launch_bounds__(512) void k_attn(const unsigned short* __restrict__ Qt,
                                              const unsigned short* __restrict__ Kt,
                                              const unsigned short* __restrict__ Vc,
                                              const float* __restrict__ mri, const float* __restrict__ cw,
                                              float* __restrict__ X) {
    __shared__ float Op[8][QW][132];   // padded: 135168 B
    int bid = blockIdx.x;                    // 0..255
    int lid = (bid & 7) * 32 + (bid >> 3);   // XCD-contiguous chunks; batch per XCD-half
    int b = lid >> 7;
    int q0 = (lid & 127) * QW;
    int t = threadIdx.x;
    int wv = t >> 6;
    int lane = t & 63;
    int lrow = lane & 15;
    int lg = lane >> 4;

    const unsigned short* Qb = Qt + (size_t)b * NN * CC;
    const unsigned short* Kb = Kt + (size_t)b * NN * CC;
    const unsigned short* Vb = Vc + (size_t)b * CC * NN;

    // hoist Q fragments: 2 q-tiles x 4 c-chunks (B-frag: col=query=lane&15, k=c)
    s16x8 qf[2][4];
#pragma unroll
    for (int qt = 0; qt < 2; qt++)
#pragma unroll
        for (int cc = 0; cc < 4; cc++)
            qf[qt][cc] = *(const s16x8*)(Qb + (size_t)(q0 + qt * 16 + lrow) * CC + cc * 32 + lg * 8);

    f32x4 acc[2][8];   // [q-tile][c-tile] of Oᵀ (col=query, row=c_local)
#pragma unroll
    for (int qt = 0; qt < 2; qt++)
#pragma unroll
        for (int ct = 0; ct < 8; ct++) acc[qt][ct] = (f32x4){0.f, 0.f, 0.f, 0.f};

    for (int kg = wv; kg < 128; kg += 8) {
        int k0 = kg * 32;
        // scores: 2 key-tiles x 2 q-tiles (Sᵀ: row=key, col=query)
        f32x4 sc[2][2];
#pragma unroll
        for (int kt = 0; kt < 2; kt++) {
            s16x8 kf[4];
#pragma unroll
            for (int cc = 0; cc < 4; cc++)
                kf[cc] = *(const s16x8*)(Kb + (size_t)(k0 + kt * 16 + lrow) * CC + cc * 32 + lg * 8);
#pragma unroll
            for (int qt = 0; qt < 2; qt++) {
                f32x4 a = (f32x4){0.f, 0.f, 0.f, 0.f};
#pragma unroll
                for (int cc = 0; cc < 4; cc++)
                    a = __builtin_amdgcn_mfma_f32_16x16x32_bf16(kf[cc], qf[qt][cc], a, 0, 0, 0);
                sc[qt][kt] = a;
            }
        }
        // softmax over each 16-key group (4 regs + lane-groups via xor 16,32) + pack bf16
        s16x8 pf[2];
#pragma unroll
        for (int qt = 0; qt < 2; qt++) {
#pragma unroll
            for (int kt = 0; kt < 2; kt++) {
                f32x4 s = sc[qt][kt];
                float m = fmaxf(fmaxf(s[0], s[1]), fmaxf(s[2], s[3]));
                m = fmaxf(m, __shfl_xor(m, 16));
                m = fmaxf(m, __shfl_xor(m, 32));
                float e0 = __expf(s[0] - m), e1 = __expf(s[1] - m);
                float e2 = __expf(s[2] - m), e3 = __expf(s[3] - m);
                float sum = e0 + e1 + e2 + e3;
                sum += __shfl_xor(sum, 16);
                sum += __shfl_xor(sum, 32);
                float inv = 1.0f / sum;
                pf[qt][kt * 4 + 0] = (short)f2bf(e0 * inv);
                pf[qt][kt * 4 + 1] = (short)f2bf(e1 * inv);
                pf[qt][kt * 4 + 2] = (short)f2bf(e2 * inv);
                pf[qt][kt * 4 + 3] = (short)f2bf(e3 * inv);
            }
        }
        // PV: A-frag = V rows (c), k-bijection: k=8g+i -> key {k0+4g+i | i<4 ; k0+16+4g+i-4}
#pragma unroll
        for (int ct = 0; ct < 8; ct++) {
            const unsigned short* vp = Vb + (size_t)(ct * 16 + lrow) * NN + k0 + 4 * lg;
            s16x4 v0 = *(const s16x4*)vp;
            s16x4 v1 = *(const s16x4*)(vp + 16);
            s16x8 vf = (s16x8){v0[0], v0[1], v0[2], v0[3], v1[0], v1[1], v1[2], v1[3]};
            acc[0][ct] = __builtin_amdgcn_mfma_f32_16x16x32_bf16(vf, pf[0], acc[0][ct], 0, 0, 0);
            acc[1][ct] = __builtin_amdgcn_mfma_f32_16x16x32_bf16(vf, pf[1], acc[1][ct], 0, 0, 0);
        }
    }
    // write partial Oᵀ to LDS (row=c_local=(lg*4+r), col=query=lrow)
#pragma unroll
    for (int qt = 0; qt < 2; qt++)
#pragma unroll
        for (int ct = 0; ct < 8; ct++)
            *(f32x4*)&Op[wv][qt * 16 + lrow][ct * 16 + lg * 4] = acc[qt][ct];
    __syncthreads();
    // combine 8 partials + epilogue X = O + mri*cw   (X layout (b,c,n))
    {
        int q = t & 31;
        int c0 = (t >> 5) * 8;
#pragma unroll
        for (int i = 0; i < 8; i++) {
            int c = c0 + i;
            float s = 0.f;
#pragma unroll
            for (int w = 0; w < 8; w++) s += Op[w][q][c];
            size_t gi = ((size_t)b * CC + c) * NN + q0 + q;
            X[gi] = s + mri[gi] * cw[b * CC + c];
        }
    }
}

// ---------------- K5: 3x3x3 conv (C->CH) + bias + ReLU + BN ----------------
__global__ __launch_bounds__(256) void k_conv3(const float* __restrict__ X,
                                               const float* __restrict__ c1w, const float* __restrict__ c1b,
                                               const float* __restrict__ g, const float* __restrict__ be,
                                               const float* __restrict__ mean, const float* __restrict__ var,
                                               float* __restrict__ Y) {
    int blk = blockIdx.x;
    int b = blk >> 10, h = (blk >> 4) & 63, d = blk & 15;
    __shared__ float wl[CC * 27];
    int t = threadIdx.x;
    for (int e = t; e < CC * 27; e += 256) wl[e] = c1w[h * CC * 27 + e];
    __syncthreads();
    int hh = t >> 4, ww = t & 15;
    const float* xb = X + (size_t)b * CC * NN;
    float acc = 0.f;
    for (int c = 0; c < CC; c++) {
        const float* xc = xb + (size_t)c * NN;
        const float* wc = &wl[c * 27];
#pragma unroll
        for (int kd = 0; kd < 3; kd++) {
            int id = d + kd - 1;
            if ((unsigned)id >= 16u) continue;
#pragma unroll
            for (int kh = 0; kh < 3; kh++) {
                int ih = hh + kh - 1;
                bool vh = (unsigned)ih < 16u;
#pragma unroll
                for (int kw = 0; kw < 3; kw++) {
                    int iw = ww + kw - 1;
                    bool v = vh && ((unsigned)iw < 16u);
                    float xv = v ? xc[id * 256 + ih * 16 + iw] : 0.f;
                    acc += xv * wc[kd * 9 + kh * 3 + kw];
                }
            }
        }
    }
    acc = fmaxf(acc + c1b[h], 0.f);
    float iv = rsqrtf(var[h] + 1e-5f);
    acc = (acc - mean[h]) * (g[h] * iv) + be[h];
    Y[((size_t)b * CHH + h) * NN + d * 256 + t] = acc;
}

// ---------------- K6: final 1x1 conv (CH->C) ----------------
__global__ __launch_bounds__(256) void k_out(const float* __restrict__ Y,
                                             const float* __restrict__ w2, const float* __restrict__ b2,
                                             float* __restrict__ out) {
    int blk = blockIdx.x;
    int b = blk >> 7, o = blk & 127;
    __shared__ float wl[CHH];
    if (threadIdx.x < CHH) wl[threadIdx.x] = w2[o * CHH + threadIdx.x];
    __syncthreads();
    float bias = b2[o];
    const float* yb = Y + (size_t)b * CHH * NN;
    for (int n = threadIdx.x; n < NN; n += 256) {
        float acc = bias;
#pragma unroll 8
        for (int hh = 0; hh < CHH; hh++) acc += wl[hh] * yb[(size_t)hh * NN + n];
        out[((size_t)b * CC + o) * NN + n] = acc;
    }
}

extern "C" void kernel_launch(void* const* d_in, const int* in_sizes, int n_in,
                              void* d_out, int out_size, void* d_ws, size_t ws_size,
                              hipStream_t stream) {
    const float* mri = (const float*)d_in[0];
    const float* pet = (const float*)d_in[1];
    const float* qw  = (const float*)d_in[2];
    const float* qb  = (const float*)d_in[3];
    const float* kw  = (const float*)d_in[4];
    const float* kb  = (const float*)d_in[5];
    const float* vw  = (const float*)d_in[6];
    const float* vb  = (const float*)d_in[7];
    const float* w1  = (const float*)d_in[8];
    const float* b1  = (const float*)d_in[9];
    const float* w2  = (const float*)d_in[10];
    const float* b2  = (const float*)d_in[11];
    const float* c1w = (const float*)d_in[12];
    const float* c1b = (const float*)d_in[13];
    const float* bg  = (const float*)d_in[14];
    const float* bbeta = (const float*)d_in[15];
    const float* bm  = (const float*)d_in[16];
    const float* bv  = (const float*)d_in[17];
    const float* c2w = (const float*)d_in[18];
    const float* c2b = (const float*)d_in[19];
    float* out = (float*)d_out;

    float* ws = (float*)d_ws;
    float* pooled = ws;                              // 256 f32
    float* cwb    = ws + 256;                        // 256 f32
    unsigned short* Qt = (unsigned short*)(ws + 512);
    unsigned short* Kt = Qt + (size_t)BB * NN * CC;
    unsigned short* Vc = Kt + (size_t)BB * NN * CC;
    float* X = (float*)(Vc + (size_t)BB * NN * CC);  // (b,c,n) f32
    float* Y = X + (size_t)BB * CC * NN;             // (b,h,n) f32

    k_pool<<<BB * CC, 256, 0, stream>>>(mri, pet, pooled);
    k_cw<<<1, 128, 0, stream>>>(pooled, w1, b1, w2, b2, cwb);
    k_qkv<<<BB * (NN / 64), 256, 0, stream>>>(mri, pet, cwb, qw, qb, kw, kb, vw, vb, Qt, Kt, Vc);
    k_attn<<<BB * (NN / QW), 512, 0, stream>>>(Qt, Kt, Vc, mri, cwb, X);
    k_conv3<<<BB * CHH * DD, 256, 0, stream>>>(X, c1w, c1b, bg, bbeta, bm, bv, Y);
    k_out<<<BB * CC, 256, 0, stream>>>(Y, c2w, c2b, out);
}

// Round 4
// 207.342 us; speedup vs baseline: 12.8834x; 2.0863x over previous
//
#include <hip/hip_runtime.h>
#include <hip/hip_bf16.h>
#include <math.h>

#define BB 2
#define CC 128
#define CHH 64
#define DD 16
#define NN 4096   // 16*16*16
#define SP 256    // 16*16
#define KTOT 3456 // 27*128

typedef float  f32x4 __attribute__((ext_vector_type(4)));
typedef short  s16x4 __attribute__((ext_vector_type(4)));
typedef short  s16x8 __attribute__((ext_vector_type(8)));

static __device__ __forceinline__ unsigned short f2bf(float x) {
    __hip_bfloat16 h = __float2bfloat16(x);
    return __builtin_bit_cast(unsigned short, h);
}

// ---------------- K0: weight prep ----------------
// Wb[h][tap*128+c] = bf16(c1w[h][c][tap]);  w2p[o][h] = bf16(c2w*g*inv);
// b2p[o] = c2b[o] + sum_h c2w[o,h]*(beta - mean*g*inv)
__global__ __launch_bounds__(256) void k_prep(const float* __restrict__ c1w, const float* __restrict__ c2w,
                                              const float* __restrict__ bg, const float* __restrict__ bbeta,
                                              const float* __restrict__ bm, const float* __restrict__ bv,
                                              const float* __restrict__ c2b,
                                              unsigned short* __restrict__ Wb,
                                              unsigned short* __restrict__ w2p,
                                              float* __restrict__ b2p) {
    int idx = blockIdx.x * 256 + threadIdx.x;
    for (int e = idx; e < CHH * KTOT; e += gridDim.x * 256) {
        int h = e / KTOT, rem = e % KTOT, tap = rem >> 7, c = rem & 127;
        Wb[e] = f2bf(c1w[(h * CC + c) * 27 + tap]);
    }
    for (int e = idx; e < CC * CHH; e += gridDim.x * 256) {
        int h = e & 63;
        float iv = rsqrtf(bv[h] + 1e-5f);
        w2p[e] = f2bf(c2w[e] * bg[h] * iv);
    }
    if (idx < CC) {
        float s = c2b[idx];
        for (int h = 0; h < CHH; h++) {
            float iv = rsqrtf(bv[h] + 1e-5f);
            s += c2w[idx * CHH + h] * (bbeta[h] - bm[h] * bg[h] * iv);
        }
        b2p[idx] = s;
    }
}

// ---------------- K1: pooled = mean over spatial of (mri+pet), per (b,c) ----------------
__global__ __launch_bounds__(256) void k_pool(const float* __restrict__ mri,
                                              const float* __restrict__ pet,
                                              float* __restrict__ pooled) {
    int bc = blockIdx.x;
    const float* m = mri + (size_t)bc * NN;
    const float* p = pet + (size_t)bc * NN;
    float s = 0.f;
    for (int i = threadIdx.x; i < NN; i += 256) s += m[i] + p[i];
    __shared__ float red[256];
    red[threadIdx.x] = s;
    __syncthreads();
    for (int off = 128; off > 0; off >>= 1) {
        if (threadIdx.x < off) red[threadIdx.x] += red[threadIdx.x + off];
        __syncthreads();
    }
    if (threadIdx.x == 0) pooled[bc] = red[0] * (1.0f / NN);
}

// ---------------- K2: channel attention MLP -> cw (B,C) ----------------
__global__ __launch_bounds__(128) void k_cw(const float* __restrict__ pooled,
                                            const float* __restrict__ w1, const float* __restrict__ b1,
                                            const float* __restrict__ w2, const float* __restrict__ b2,
                                            float* __restrict__ cw) {
    __shared__ float pl[BB * CC];
    __shared__ float tl[BB * CHH];
    int t = threadIdx.x;
    pl[t] = pooled[t];
    pl[t + 128] = pooled[t + 128];
    __syncthreads();
    {
        int b = t >> 6, h = t & 63;
        float acc = b1[h];
        for (int c = 0; c < CC; c++) acc += pl[b * CC + c] * w1[h * CC + c];
        tl[b * CHH + h] = fmaxf(acc, 0.f);
    }
    __syncthreads();
    for (int b = 0; b < BB; b++) {
        float acc = b2[t];
        for (int h = 0; h < CHH; h++) acc += tl[b * CHH + h] * w2[t * CHH + h];
        cw[b * CC + t] = 1.f / (1.f + __expf(-acc));
    }
}

// ---------------- K3: Q/K/V 1x1 convs with cw folded; bf16 outputs ----------------
// Qt, Kt: (b, n, c) bf16 ; Vc: (b, c, n) bf16
__global__ __launch_bounds__(256) void k_qkv(const float* __restrict__ mri, const float* __restrict__ pet,
                                             const float* __restrict__ cw,
                                             const float* __restrict__ qw, const float* __restrict__ qb,
                                             const float* __restrict__ kw, const float* __restrict__ kb,
                                             const float* __restrict__ vw, const float* __restrict__ vb,
                                             unsigned short* __restrict__ Qt, unsigned short* __restrict__ Kt,
                                             unsigned short* __restrict__ Vc) {
    int blk = blockIdx.x;
    int b = blk >> 6;
    int n0 = (blk & 63) * 64;
    __shared__ float am[CC * 64];
    __shared__ float ap[CC * 64];
    int t = threadIdx.x;
    for (int e = t; e < CC * 64; e += 256) {
        int c = e >> 6, j = e & 63;
        float cwv = cw[b * CC + c];
        size_t g = (size_t)(b * CC + c) * NN + n0 + j;
        am[e] = mri[g] * cwv;
        ap[e] = pet[g] * cwv;
    }
    __syncthreads();
    int o = t & 127, half = t >> 7;
    const int jb = half * 32;
    {
        float acc[32];
        float bias = qb[o];
#pragma unroll
        for (int j = 0; j < 32; j++) acc[j] = bias;
        for (int c = 0; c < CC; c++) {
            float wv = qw[o * CC + c];
            const float* row = &am[c * 64 + jb];
#pragma unroll
            for (int j = 0; j < 32; j++) acc[j] += wv * row[j];
        }
#pragma unroll
        for (int j = 0; j < 32; j++) Qt[((size_t)b * NN + n0 + jb + j) * CC + o] = f2bf(acc[j]);
    }
    {
        float acc[32];
        float bias = kb[o];
#pragma unroll
        for (int j = 0; j < 32; j++) acc[j] = bias;
        for (int c = 0; c < CC; c++) {
            float wv = kw[o * CC + c];
            const float* row = &ap[c * 64 + jb];
#pragma unroll
            for (int j = 0; j < 32; j++) acc[j] += wv * row[j];
        }
#pragma unroll
        for (int j = 0; j < 32; j++) Kt[((size_t)b * NN + n0 + jb + j) * CC + o] = f2bf(acc[j]);
    }
    {
        float acc[32];
        float bias = vb[o];
#pragma unroll
        for (int j = 0; j < 32; j++) acc[j] = bias;
        for (int c = 0; c < CC; c++) {
            float wv = vw[o * CC + c];
            const float* row = &ap[c * 64 + jb];
#pragma unroll
            for (int j = 0; j < 32; j++) acc[j] += wv * row[j];
        }
#pragma unroll
        for (int j = 0; j < 32; j++) Vc[((size_t)b * CC + o) * NN + n0 + jb + j] = f2bf(acc[j]);
    }
}

// ---------------- K4: MFMA attention ----------------
// S^T = K*Q^T per 16-key tile (= one softmax group); softmax in-register;
// P regs are directly the PV B-fragment; O accumulated as O^T[c][q].
// Epilogue writes X as bf16 (b, n, c) for the conv MFMA.
#define QW 32
__global__ __launch_bounds__(512) void k_attn(const unsigned short* __restrict__ Qt,
                                              const unsigned short* __restrict__ Kt,
                                              const unsigned short* __restrict__ Vc,
                                              const float* __restrict__ mri, const float* __restrict__ cw,
                                              unsigned short* __restrict__ Xb) {
    __shared__ float Op[8][QW][132];   // padded: 135168 B
    int bid = blockIdx.x;                    // 0..255
    int lid = (bid & 7) * 32 + (bid >> 3);   // XCD-contiguous chunks
    int b = lid >> 7;
    int q0 = (lid & 127) * QW;
    int t = threadIdx.x;
    int wv = t >> 6;
    int lane = t & 63;
    int lrow = lane & 15;
    int lg = lane >> 4;

    const unsigned short* Qb = Qt + (size_t)b * NN * CC;
    const unsigned short* Kb = Kt + (size_t)b * NN * CC;
    const unsigned short* Vb = Vc + (size_t)b * CC * NN;

    s16x8 qf[2][4];
#pragma unroll
    for (int qt = 0; qt < 2; qt++)
#pragma unroll
        for (int cc = 0; cc < 4; cc++)
            qf[qt][cc] = *(const s16x8*)(Qb + (size_t)(q0 + qt * 16 + lrow) * CC + cc * 32 + lg * 8);

    f32x4 acc[2][8];
#pragma unroll
    for (int qt = 0; qt < 2; qt++)
#pragma unroll
        for (int ct = 0; ct < 8; ct++) acc[qt][ct] = (f32x4){0.f, 0.f, 0.f, 0.f};

    for (int kg = wv; kg < 128; kg += 8) {
        int k0 = kg * 32;
        f32x4 sc[2][2];
#pragma unroll
        for (int kt = 0; kt < 2; kt++) {
            s16x8 kf[4];
#pragma unroll
            for (int cc = 0; cc < 4; cc++)
                kf[cc] = *(const s16x8*)(Kb + (size_t)(k0 + kt * 16 + lrow) * CC + cc * 32 + lg * 8);
#pragma unroll
            for (int qt = 0; qt < 2; qt++) {
                f32x4 a = (f32x4){0.f, 0.f, 0.f, 0.f};
#pragma unroll
                for (int cc = 0; cc < 4; cc++)
                    a = __builtin_amdgcn_mfma_f32_16x16x32_bf16(kf[cc], qf[qt][cc], a, 0, 0, 0);
                sc[qt][kt] = a;
            }
        }
        s16x8 pf[2];
#pragma unroll
        for (int qt = 0; qt < 2; qt++) {
#pragma unroll
            for (int kt = 0; kt < 2; kt++) {
                f32x4 s = sc[qt][kt];
                float m = fmaxf(fmaxf(s[0], s[1]), fmaxf(s[2], s[3]));
                m = fmaxf(m, __shfl_xor(m, 16));
                m = fmaxf(m, __shfl_xor(m, 32));
                float e0 = __expf(s[0] - m), e1 = __expf(s[1] - m);
                float e2 = __expf(s[2] - m), e3 = __expf(s[3] - m);
                float sum = e0 + e1 + e2 + e3;
                sum += __shfl_xor(sum, 16);
                sum += __shfl_xor(sum, 32);
                float inv = 1.0f / sum;
                pf[qt][kt * 4 + 0] = (short)f2bf(e0 * inv);
                pf[qt][kt * 4 + 1] = (short)f2bf(e1 * inv);
                pf[qt][kt * 4 + 2] = (short)f2bf(e2 * inv);
                pf[qt][kt * 4 + 3] = (short)f2bf(e3 * inv);
            }
        }
#pragma unroll
        for (int ct = 0; ct < 8; ct++) {
            const unsigned short* vp = Vb + (size_t)(ct * 16 + lrow) * NN + k0 + 4 * lg;
            s16x4 v0 = *(const s16x4*)vp;
            s16x4 v1 = *(const s16x4*)(vp + 16);
            s16x8 vf = (s16x8){v0[0], v0[1], v0[2], v0[3], v1[0], v1[1], v1[2], v1[3]};
            acc[0][ct] = __builtin_amdgcn_mfma_f32_16x16x32_bf16(vf, pf[0], acc[0][ct], 0, 0, 0);
            acc[1][ct] = __builtin_amdgcn_mfma_f32_16x16x32_bf16(vf, pf[1], acc[1][ct], 0, 0, 0);
        }
    }
#pragma unroll
    for (int qt = 0; qt < 2; qt++)
#pragma unroll
        for (int ct = 0; ct < 8; ct++)
            *(f32x4*)&Op[wv][qt * 16 + lrow][ct * 16 + lg * 4] = acc[qt][ct];
    __syncthreads();
    // combine partials + epilogue: Xb(b,n,c) = O + mri*cw (bf16)
    {
        int q = t & 31;
        int c0 = (t >> 5) * 8;
        s16x8 xv;
#pragma unroll
        for (int i = 0; i < 8; i++) {
            int c = c0 + i;
            float s = 0.f;
#pragma unroll
            for (int w = 0; w < 8; w++) s += Op[w][q][c];
            size_t gi = ((size_t)b * CC + c) * NN + q0 + q;
            xv[i] = (short)f2bf(s + mri[gi] * cw[b * CC + c]);
        }
        *(s16x8*)&Xb[((size_t)b * NN + q0 + q) * CC + c0] = xv;
    }
}

// ---------------- K5: 3x3x3 conv as implicit-GEMM MFMA + bias + ReLU ----------------
// Y[b,h,n] -> stored bf16 (b, n, h). M=16 h_out, N=16 w (one image row), K=tap*c.
__global__ __launch_bounds__(256) void k_conv3(const unsigned short* __restrict__ Xb,
                                               const unsigned short* __restrict__ Wb,
                                               const float* __restrict__ c1b,
                                               unsigned short* __restrict__ Yb) {
    int bid = blockIdx.x;             // 512
    int b = bid >> 8;
    int d = (bid >> 4) & 15;
    int h0 = ((bid >> 2) & 3) * 16;
    int hp = (bid & 3) * 4;
    int t = threadIdx.x;
    int wv = t >> 6;
    int himg = hp + wv;
    int lane = t & 63;
    int lrow = lane & 15, lg = lane >> 4;

    const unsigned short* Wrow = Wb + (size_t)(h0 + lrow) * KTOT + lg * 8;
    const unsigned short* Xbase = Xb + (size_t)b * NN * CC + lg * 8;
    const s16x8 z8 = (s16x8){0, 0, 0, 0, 0, 0, 0, 0};

    f32x4 acc = (f32x4){0.f, 0.f, 0.f, 0.f};
    for (int kd = 0; kd < 3; kd++) {
        int dd2 = d + kd - 1;
        if ((unsigned)dd2 >= 16u) continue;
        for (int kh = 0; kh < 3; kh++) {
            int hh2 = himg + kh - 1;
            if ((unsigned)hh2 >= 16u) continue;
#pragma unroll
            for (int kw = 0; kw < 3; kw++) {
                int ww2 = lrow + kw - 1;
                bool okw = (unsigned)ww2 < 16u;
                int tap = (kd * 3 + kh) * 3 + kw;
                const unsigned short* wtap = Wrow + tap * CC;
                const unsigned short* xpos = Xbase + (size_t)(dd2 * 256 + hh2 * 16 + ww2) * CC;
                s16x8 a0 = *(const s16x8*)(wtap);
                s16x8 a1 = *(const s16x8*)(wtap + 32);
                s16x8 a2 = *(const s16x8*)(wtap + 64);
                s16x8 a3 = *(const s16x8*)(wtap + 96);
                s16x8 b0 = okw ? *(const s16x8*)(xpos) : z8;
                s16x8 b1 = okw ? *(const s16x8*)(xpos + 32) : z8;
                s16x8 b2 = okw ? *(const s16x8*)(xpos + 64) : z8;
                s16x8 b3 = okw ? *(const s16x8*)(xpos + 96) : z8;
                acc = __builtin_amdgcn_mfma_f32_16x16x32_bf16(a0, b0, acc, 0, 0, 0);
                acc = __builtin_amdgcn_mfma_f32_16x16x32_bf16(a1, b1, acc, 0, 0, 0);
                acc = __builtin_amdgcn_mfma_f32_16x16x32_bf16(a2, b2, acc, 0, 0, 0);
                acc = __builtin_amdgcn_mfma_f32_16x16x32_bf16(a3, b3, acc, 0, 0, 0);
            }
        }
    }
    // epilogue: bias + ReLU -> Yb (b, n, h) bf16   (BN folded into k_out weights)
    int hloc = h0 + lg * 4;
    int n = d * 256 + himg * 16 + lrow;
    s16x4 yv;
#pragma unroll
    for (int r = 0; r < 4; r++) {
        float y = fmaxf(acc[r] + c1b[hloc + r], 0.f);
        yv[r] = (short)f2bf(y);
    }
    *(s16x4*)&Yb[((size_t)b * NN + n) * CHH + hloc] = yv;
}

// ---------------- K6: final 1x1 conv (CH->C) via MFMA, BN pre-folded ----------------
__global__ __launch_bounds__(256) void k_out(const unsigned short* __restrict__ Yb,
                                             const unsigned short* __restrict__ w2p,
                                             const float* __restrict__ b2p,
                                             float* __restrict__ out) {
    int bid = blockIdx.x;    // 256
    int b = bid >> 7, n0 = (bid & 127) * 32;
    int t = threadIdx.x;
    int wv = t >> 6, lane = t & 63;
    int lrow = lane & 15, lg = lane >> 4;
    int o0 = wv * 32;

    f32x4 acc[2][2];
#pragma unroll
    for (int m = 0; m < 2; m++)
#pragma unroll
        for (int nt = 0; nt < 2; nt++) acc[m][nt] = (f32x4){0.f, 0.f, 0.f, 0.f};

#pragma unroll
    for (int ks = 0; ks < 2; ks++) {
        s16x8 a0 = *(const s16x8*)&w2p[(o0 + lrow) * CHH + ks * 32 + lg * 8];
        s16x8 a1 = *(const s16x8*)&w2p[(o0 + 16 + lrow) * CHH + ks * 32 + lg * 8];
        s16x8 f0 = *(const s16x8*)&Yb[((size_t)b * NN + n0 + lrow) * CHH + ks * 32 + lg * 8];
        s16x8 f1 = *(const s16x8*)&Yb[((size_t)b * NN + n0 + 16 + lrow) * CHH + ks * 32 + lg * 8];
        acc[0][0] = __builtin_amdgcn_mfma_f32_16x16x32_bf16(a0, f0, acc[0][0], 0, 0, 0);
        acc[0][1] = __builtin_amdgcn_mfma_f32_16x16x32_bf16(a0, f1, acc[0][1], 0, 0, 0);
        acc[1][0] = __builtin_amdgcn_mfma_f32_16x16x32_bf16(a1, f0, acc[1][0], 0, 0, 0);
        acc[1][1] = __builtin_amdgcn_mfma_f32_16x16x32_bf16(a1, f1, acc[1][1], 0, 0, 0);
    }
#pragma unroll
    for (int m = 0; m < 2; m++) {
#pragma unroll
        for (int r = 0; r < 4; r++) {
            int o = o0 + m * 16 + lg * 4 + r;
            float bias = b2p[o];
#pragma unroll
            for (int nt = 0; nt < 2; nt++) {
                int n = n0 + nt * 16 + lrow;
                out[((size_t)b * CC + o) * NN + n] = acc[m][nt][r] + bias;
            }
        }
    }
}

extern "C" void kernel_launch(void* const* d_in, const int* in_sizes, int n_in,
                              void* d_out, int out_size, void* d_ws, size_t ws_size,
                              hipStream_t stream) {
    const float* mri = (const float*)d_in[0];
    const float* pet = (const float*)d_in[1];
    const float* qw  = (const float*)d_in[2];
    const float* qb  = (const float*)d_in[3];
    const float* kw  = (const float*)d_in[4];
    const float* kb  = (const float*)d_in[5];
    const float* vw  = (const float*)d_in[6];
    const float* vb  = (const float*)d_in[7];
    const float* w1  = (const float*)d_in[8];
    const float* b1  = (const float*)d_in[9];
    const float* w2  = (const float*)d_in[10];
    const float* b2  = (const float*)d_in[11];
    const float* c1w = (const float*)d_in[12];
    const float* c1b = (const float*)d_in[13];
    const float* bg  = (const float*)d_in[14];
    const float* bbeta = (const float*)d_in[15];
    const float* bm  = (const float*)d_in[16];
    const float* bv  = (const float*)d_in[17];
    const float* c2w = (const float*)d_in[18];
    const float* c2b = (const float*)d_in[19];
    float* out = (float*)d_out;

    float* ws = (float*)d_ws;
    float* pooled = ws;                               // 256 f32
    float* cwb    = ws + 256;                         // 256 f32
    float* b2p    = ws + 512;                         // 128 f32
    unsigned short* Qt  = (unsigned short*)(ws + 1024);
    unsigned short* Kt  = Qt + (size_t)BB * NN * CC;
    unsigned short* Vc  = Kt + (size_t)BB * NN * CC;
    unsigned short* Xb  = Vc + (size_t)BB * NN * CC;  // (b,n,c) bf16
    unsigned short* Yb  = Xb + (size_t)BB * NN * CC;  // (b,n,h) bf16
    unsigned short* Wb  = Yb + (size_t)BB * NN * CHH; // 64*3456 bf16
    unsigned short* w2p = Wb + (size_t)CHH * KTOT;    // 128*64 bf16

    k_prep<<<64, 256, 0, stream>>>(c1w, c2w, bg, bbeta, bm, bv, c2b, Wb, w2p, b2p);
    k_pool<<<BB * CC, 256, 0, stream>>>(mri, pet, pooled);
    k_cw<<<1, 128, 0, stream>>>(pooled, w1, b1, w2, b2, cwb);
    k_qkv<<<BB * (NN / 64), 256, 0, stream>>>(mri, pet, cwb, qw, qb, kw, kb, vw, vb, Qt, Kt, Vc);
    k_attn<<<BB * (NN / QW), 512, 0, stream>>>(Qt, Kt, Vc, mri, cwb, Xb);
    k_conv3<<<512, 256, 0, stream>>>(Xb, Wb, c1b, Yb);
    k_out<<<256, 256, 0, stream>>>(Yb, w2p, b2p, out);
}